// Round 1
// 4635.172 us; speedup vs baseline: 1.1271x; 1.1271x over previous
//
#include <hip/hip_runtime.h>
#include <math.h>

#define T_TOKENS 16384
#define DIM      7168
#define NE       256
#define NG       8
#define GSZ      32
#define TOPKG    4
#define TOPK     8
#define RSCALE   2.5

#define BM      64          // tokens per block
#define BK      16
#define THREADS 512
#define NTILES  (DIM / BK)  // 448

// Register budget: we need ~180 live VGPRs (acc[8][4] fp64 = 64, a_cur/a_nxt
// float4[8] = 64, B prefetch + addressing). __launch_bounds__(512,2) only sets
// the waves/EU MINIMUM -> the backend still targeted high occupancy (budget
// ~60-64 VGPRs) and spilled 14.6 GB/dispatch to scratch (measured: VGPR_Count=60,
// WRITE_SIZE=1.46e7 KB). amdgpu_waves_per_eu(2,2) pins min AND max occupancy at
// 2 waves/EU (1 WG/CU), raising the allocator budget to 256 VGPRs -> no spill.
__global__ __launch_bounds__(THREADS)
__attribute__((amdgpu_waves_per_eu(2, 2)))
void gate_kernel(
    const float* __restrict__ x,      // [T][DIM] fp32
    const float* __restrict__ w,      // [NE][DIM] fp32
    const float* __restrict__ bias,   // [NE] fp32
    float* __restrict__ out_w,        // [T][8]
    float* __restrict__ out_i)        // [T][8] (indices as float)
{
    // Bs[kk][pos] fp64, pos = half*128 + lane*2 + j  <->  expert e = half*128 + j*64 + lane
    __shared__ __align__(16) double Bs[BK * NE];     // 32 KB
    __shared__ __align__(16) double scr[8 * NE];     // 16 KB: per-wave unbiased sigmoid
    __shared__ __align__(16) double bias_d[NE];      // 2 KB

    const int tid  = threadIdx.x;
    const int lane = tid & 63;
    const int wave_u = __builtin_amdgcn_readfirstlane(tid >> 6);  // 0..7, uniform

    if (tid < NE) bias_d[tid] = (double)bias[tid];

    // ---- staging role: this thread loads experts (e0,e1) at k-chunk kc_s ----
    const int half = wave_u >> 2;     // 0/1
    const int kc_s = wave_u & 3;      // 0..3
    const int e0   = half * 128 + lane;
    const int e1   = e0 + 64;
    const float* wp0 = w + (size_t)e0 * DIM + kc_s * 4;
    const float* wp1 = w + (size_t)e1 * DIM + kc_s * 4;

    const int tok_base = blockIdx.x * BM + wave_u * 8;   // uniform per wave

    double acc[8][4];
#pragma unroll
    for (int t = 0; t < 8; ++t)
#pragma unroll
        for (int j = 0; j < 4; ++j) acc[t][j] = 0.0;

    // prefetch B tile 0 into regs
    float4 f0 = *(const float4*)(wp0);
    float4 f1 = *(const float4*)(wp1);

    // prefetch A chunk (kc=0 of tile 0): wave-uniform addresses
    float4 a_cur[8], a_nxt[8];
#pragma unroll
    for (int t = 0; t < 8; ++t)
        a_cur[t] = *(const float4*)(x + (size_t)(tok_base + t) * DIM);

    for (int tile = 0; tile < NTILES; ++tile) {
        const int k0 = tile * BK;

        __syncthreads();   // previous tile's Bs reads complete (also covers bias_d init)
#pragma unroll
        for (int c = 0; c < 4; ++c) {
            double2 d;
            d.x = (double)((&f0.x)[c]);
            d.y = (double)((&f1.x)[c]);
            *(double2*)&Bs[(kc_s * 4 + c) * NE + half * 128 + lane * 2] = d;
        }
        __syncthreads();   // Bs ready

        if (tile + 1 < NTILES) {       // register-prefetch next B tile
            f0 = *(const float4*)(wp0 + (size_t)(tile + 1) * BK);
            f1 = *(const float4*)(wp1 + (size_t)(tile + 1) * BK);
        }

#pragma unroll
        for (int kc = 0; kc < 4; ++kc) {
            int knext = k0 + (kc + 1) * 4;       // at kc=3 this is next tile's chunk 0
            if (knext >= DIM) knext = 0;         // last-tile guard (values discarded)
#pragma unroll
            for (int t = 0; t < 8; ++t)
                a_nxt[t] = *(const float4*)(x + (size_t)(tok_base + t) * DIM + knext);

#pragma unroll
            for (int c = 0; c < 4; ++c) {
                const int kk = kc * 4 + c;
                double2 b01 = *(const double2*)&Bs[kk * NE + lane * 2];
                double2 b23 = *(const double2*)&Bs[kk * NE + 128 + lane * 2];
#pragma unroll
                for (int t = 0; t < 8; ++t) {
                    double a = (double)((&a_cur[t].x)[c]);
                    acc[t][0] = fma(a, b01.x, acc[t][0]);
                    acc[t][1] = fma(a, b01.y, acc[t][1]);
                    acc[t][2] = fma(a, b23.x, acc[t][2]);
                    acc[t][3] = fma(a, b23.y, acc[t][3]);
                }
            }
#pragma unroll
            for (int t = 0; t < 8; ++t) a_cur[t] = a_nxt[t];
        }
    }

    // ================= routing (per-wave independent, fp64) =================
    double* myscr = scr + wave_u * NE;

    double bias_j[4];
#pragma unroll
    for (int j = 0; j < 4; ++j) bias_j[j] = bias_d[j * 64 + lane];

    for (int tk = 0; tk < 8; ++tk) {
        // sigmoid (fp64) of this token's 4 expert scores; stash unbiased in LDS
        double sg[4];
#pragma unroll
        for (int j = 0; j < 4; ++j) {
            sg[j] = 1.0 / (1.0 + exp(-acc[tk][j]));
            myscr[j * 64 + lane] = sg[j];
        }
        asm volatile("s_waitcnt lgkmcnt(0)" ::: "memory");  // same-wave LDS visibility

        // ---- group scores: top-2 sum of biased scores per group (8 lanes/group) ----
        const int g    = lane >> 3;
        const int slot = lane & 7;
        const int eb   = g * GSZ + slot * 4;
        double2 s01  = *(const double2*)&myscr[eb];
        double2 s23  = *(const double2*)&myscr[eb + 2];
        double2 b01v = *(const double2*)&bias_d[eb];
        double2 b23v = *(const double2*)&bias_d[eb + 2];
        double c0 = s01.x + b01v.x, c1 = s01.y + b01v.y;
        double c2 = s23.x + b23v.x, c3 = s23.y + b23v.y;
        double m1 = fmax(c0, c1), m2 = fmin(c0, c1);
        if (c2 > m1) { m2 = m1; m1 = c2; } else m2 = fmax(m2, c2);
        if (c3 > m1) { m2 = m1; m1 = c3; } else m2 = fmax(m2, c3);
#pragma unroll
        for (int off = 1; off <= 4; off <<= 1) {
            double o1 = __shfl_xor(m1, off);
            double o2 = __shfl_xor(m2, off);
            double nm1 = fmax(m1, o1);
            double nm2 = fmax(fmin(m1, o1), fmax(m2, o2));
            m1 = nm1; m2 = nm2;
        }
        double gs_local = m1 + m2;
        double gsv[NG];
#pragma unroll
        for (int gg = 0; gg < NG; ++gg) gsv[gg] = __shfl(gs_local, gg * 8);

        // top-4 groups (stable: ties -> lower group index)
        int selmask = 0;
#pragma unroll
        for (int gg = 0; gg < NG; ++gg) {
            int rank = 0;
#pragma unroll
            for (int h = 0; h < NG; ++h)
                if (gsv[h] > gsv[gg] || (gsv[h] == gsv[gg] && h < gg)) rank++;
            if (rank < TOPKG) selmask |= (1 << gg);
        }

        // ---- top-8 experts: register-resident butterfly extraction ----
        double cv[4];
#pragma unroll
        for (int j = 0; j < 4; ++j) {
            int grp = j * 2 + (lane >> 5);       // group of expert j*64+lane
            cv[j] = ((selmask >> grp) & 1) ? (sg[j] + bias_j[j]) : -INFINITY;
        }

        double ssum = 0.0, my_u = 0.0;
        int my_i = 0;
#pragma unroll
        for (int r = 0; r < TOPK; ++r) {
            double bv = cv[0], bu = sg[0];
            int bi = lane;
#pragma unroll
            for (int j = 1; j < 4; ++j) {
                if (cv[j] > bv) { bv = cv[j]; bu = sg[j]; bi = j * 64 + lane; }
            }
#pragma unroll
            for (int off = 1; off < 64; off <<= 1) {
                double ov = __shfl_xor(bv, off);
                double ou = __shfl_xor(bu, off);
                int    oi = __shfl_xor(bi, off);
                if (ov > bv || (ov == bv && oi < bi)) { bv = ov; bu = ou; bi = oi; }
            }
            ssum += bu;
            if (lane == r) { my_u = bu; my_i = bi; }
#pragma unroll
            for (int j = 0; j < 4; ++j)
                if (j * 64 + lane == bi) cv[j] = -INFINITY;
        }

        const double scale = RSCALE / ssum;
        const size_t obase = (size_t)(tok_base + tk) * TOPK;
        if (lane < TOPK) {
            out_w[obase + lane] = (float)(my_u * scale);
            out_i[obase + lane] = (float)my_i;
        }
    }
}

extern "C" void kernel_launch(void* const* d_in, const int* in_sizes, int n_in,
                              void* d_out, int out_size, void* d_ws, size_t ws_size,
                              hipStream_t stream) {
    const float* x    = (const float*)d_in[0];
    const float* w    = (const float*)d_in[1];
    const float* bias = (const float*)d_in[2];

    float* out_w = (float*)d_out;
    float* out_i = out_w + (size_t)T_TOKENS * TOPK;

    dim3 grid(T_TOKENS / BM);
    dim3 block(THREADS);
    gate_kernel<<<grid, block, 0, stream>>>(x, w, bias, out_w, out_i);
}

// Round 2
// 2175.731 us; speedup vs baseline: 2.4012x; 2.1304x over previous
//
#include <hip/hip_runtime.h>
#include <math.h>

#define T_TOKENS 16384
#define DIM      7168
#define NE       256
#define NG       8
#define GSZ      32
#define TOPKG    4
#define TOPK     8
#define RSCALE   2.5

#define NT      4           // tokens per wave (was 8: spilled at 120-VGPR budget)
#define BM      (8 * NT)    // 32 tokens per block
#define BK      16
#define THREADS 512
#define NTILES  (DIM / BK)  // 448

// R1 post-mortem: amdgpu_waves_per_eu(2,2) yielded a 128-VGPR budget (alloc 120,
// 4 waves/EU target), NOT 256 -> acc[8][4] fp64 + a[8]x2 float4 (~180 live) still
// spilled 14.6 GB/dispatch. R2: shrink demand instead of fighting the allocator:
// 4 tokens/wave -> acc[4][4]=32 + a[4]x2=32 + B prefetch/addr ~= 100 VGPRs, fits.
__global__ __launch_bounds__(THREADS)
__attribute__((amdgpu_waves_per_eu(2, 4)))
void gate_kernel(
    const float* __restrict__ x,      // [T][DIM] fp32
    const float* __restrict__ w,      // [NE][DIM] fp32
    const float* __restrict__ bias,   // [NE] fp32
    float* __restrict__ out_w,        // [T][8]
    float* __restrict__ out_i)        // [T][8] (indices as float)
{
    // Bs[kk][pos] fp64, pos = half*128 + lane*2 + j  <->  expert e = half*128 + j*64 + lane
    __shared__ __align__(16) double Bs[BK * NE];     // 32 KB
    __shared__ __align__(16) double scr[8 * NE];     // 16 KB: per-wave unbiased sigmoid
    __shared__ __align__(16) double bias_d[NE];      // 2 KB

    const int tid  = threadIdx.x;
    const int lane = tid & 63;
    const int wave_u = __builtin_amdgcn_readfirstlane(tid >> 6);  // 0..7, uniform

    if (tid < NE) bias_d[tid] = (double)bias[tid];

    // ---- staging role: this thread loads experts (e0,e1) at k-chunk kc_s ----
    const int half = wave_u >> 2;     // 0/1
    const int kc_s = wave_u & 3;      // 0..3
    const int e0   = half * 128 + lane;
    const int e1   = e0 + 64;
    const float* wp0 = w + (size_t)e0 * DIM + kc_s * 4;
    const float* wp1 = w + (size_t)e1 * DIM + kc_s * 4;

    const int tok_base = blockIdx.x * BM + wave_u * NT;   // uniform per wave

    double acc[NT][4];
#pragma unroll
    for (int t = 0; t < NT; ++t)
#pragma unroll
        for (int j = 0; j < 4; ++j) acc[t][j] = 0.0;

    // prefetch B tile 0 into regs
    float4 f0 = *(const float4*)(wp0);
    float4 f1 = *(const float4*)(wp1);

    // prefetch A chunk (kc=0 of tile 0): wave-uniform addresses
    float4 a_cur[NT], a_nxt[NT];
#pragma unroll
    for (int t = 0; t < NT; ++t)
        a_cur[t] = *(const float4*)(x + (size_t)(tok_base + t) * DIM);

    for (int tile = 0; tile < NTILES; ++tile) {
        const int k0 = tile * BK;

        __syncthreads();   // previous tile's Bs reads complete (also covers bias_d init)
#pragma unroll
        for (int c = 0; c < 4; ++c) {
            double2 d;
            d.x = (double)((&f0.x)[c]);
            d.y = (double)((&f1.x)[c]);
            *(double2*)&Bs[(kc_s * 4 + c) * NE + half * 128 + lane * 2] = d;
        }
        __syncthreads();   // Bs ready

        if (tile + 1 < NTILES) {       // register-prefetch next B tile
            f0 = *(const float4*)(wp0 + (size_t)(tile + 1) * BK);
            f1 = *(const float4*)(wp1 + (size_t)(tile + 1) * BK);
        }

#pragma unroll
        for (int kc = 0; kc < 4; ++kc) {
            int knext = k0 + (kc + 1) * 4;       // at kc=3 this is next tile's chunk 0
            if (knext >= DIM) knext = 0;         // last-tile guard (values discarded)
#pragma unroll
            for (int t = 0; t < NT; ++t)
                a_nxt[t] = *(const float4*)(x + (size_t)(tok_base + t) * DIM + knext);

#pragma unroll
            for (int c = 0; c < 4; ++c) {
                const int kk = kc * 4 + c;
                double2 b01 = *(const double2*)&Bs[kk * NE + lane * 2];
                double2 b23 = *(const double2*)&Bs[kk * NE + 128 + lane * 2];
#pragma unroll
                for (int t = 0; t < NT; ++t) {
                    double a = (double)((&a_cur[t].x)[c]);
                    acc[t][0] = fma(a, b01.x, acc[t][0]);
                    acc[t][1] = fma(a, b01.y, acc[t][1]);
                    acc[t][2] = fma(a, b23.x, acc[t][2]);
                    acc[t][3] = fma(a, b23.y, acc[t][3]);
                }
            }
#pragma unroll
            for (int t = 0; t < NT; ++t) a_cur[t] = a_nxt[t];
        }
    }

    // ================= routing (per-wave independent, fp64) =================
    double* myscr = scr + wave_u * NE;

    double bias_j[4];
#pragma unroll
    for (int j = 0; j < 4; ++j) bias_j[j] = bias_d[j * 64 + lane];

    for (int tk = 0; tk < NT; ++tk) {
        // sigmoid (fp64) of this token's 4 expert scores; stash unbiased in LDS
        double sg[4];
#pragma unroll
        for (int j = 0; j < 4; ++j) {
            sg[j] = 1.0 / (1.0 + exp(-acc[tk][j]));
            myscr[j * 64 + lane] = sg[j];
        }
        asm volatile("s_waitcnt lgkmcnt(0)" ::: "memory");  // same-wave LDS visibility

        // ---- group scores: top-2 sum of biased scores per group (8 lanes/group) ----
        const int g    = lane >> 3;
        const int slot = lane & 7;
        const int eb   = g * GSZ + slot * 4;
        double2 s01  = *(const double2*)&myscr[eb];
        double2 s23  = *(const double2*)&myscr[eb + 2];
        double2 b01v = *(const double2*)&bias_d[eb];
        double2 b23v = *(const double2*)&bias_d[eb + 2];
        double c0 = s01.x + b01v.x, c1 = s01.y + b01v.y;
        double c2 = s23.x + b23v.x, c3 = s23.y + b23v.y;
        double m1 = fmax(c0, c1), m2 = fmin(c0, c1);
        if (c2 > m1) { m2 = m1; m1 = c2; } else m2 = fmax(m2, c2);
        if (c3 > m1) { m2 = m1; m1 = c3; } else m2 = fmax(m2, c3);
#pragma unroll
        for (int off = 1; off <= 4; off <<= 1) {
            double o1 = __shfl_xor(m1, off);
            double o2 = __shfl_xor(m2, off);
            double nm1 = fmax(m1, o1);
            double nm2 = fmax(fmin(m1, o1), fmax(m2, o2));
            m1 = nm1; m2 = nm2;
        }
        double gs_local = m1 + m2;
        double gsv[NG];
#pragma unroll
        for (int gg = 0; gg < NG; ++gg) gsv[gg] = __shfl(gs_local, gg * 8);

        // top-4 groups (stable: ties -> lower group index)
        int selmask = 0;
#pragma unroll
        for (int gg = 0; gg < NG; ++gg) {
            int rank = 0;
#pragma unroll
            for (int h = 0; h < NG; ++h)
                if (gsv[h] > gsv[gg] || (gsv[h] == gsv[gg] && h < gg)) rank++;
            if (rank < TOPKG) selmask |= (1 << gg);
        }

        // ---- top-8 experts: register-resident butterfly extraction ----
        double cv[4];
#pragma unroll
        for (int j = 0; j < 4; ++j) {
            int grp = j * 2 + (lane >> 5);       // group of expert j*64+lane
            cv[j] = ((selmask >> grp) & 1) ? (sg[j] + bias_j[j]) : -INFINITY;
        }

        double ssum = 0.0, my_u = 0.0;
        int my_i = 0;
#pragma unroll
        for (int r = 0; r < TOPK; ++r) {
            double bv = cv[0], bu = sg[0];
            int bi = lane;
#pragma unroll
            for (int j = 1; j < 4; ++j) {
                if (cv[j] > bv) { bv = cv[j]; bu = sg[j]; bi = j * 64 + lane; }
            }
#pragma unroll
            for (int off = 1; off < 64; off <<= 1) {
                double ov = __shfl_xor(bv, off);
                double ou = __shfl_xor(bu, off);
                int    oi = __shfl_xor(bi, off);
                if (ov > bv || (ov == bv && oi < bi)) { bv = ov; bu = ou; bi = oi; }
            }
            ssum += bu;
            if (lane == r) { my_u = bu; my_i = bi; }
#pragma unroll
            for (int j = 0; j < 4; ++j)
                if (j * 64 + lane == bi) cv[j] = -INFINITY;
        }

        const double scale = RSCALE / ssum;
        const size_t obase = (size_t)(tok_base + tk) * TOPK;
        if (lane < TOPK) {
            out_w[obase + lane] = (float)(my_u * scale);
            out_i[obase + lane] = (float)my_i;
        }
    }
}

extern "C" void kernel_launch(void* const* d_in, const int* in_sizes, int n_in,
                              void* d_out, int out_size, void* d_ws, size_t ws_size,
                              hipStream_t stream) {
    const float* x    = (const float*)d_in[0];
    const float* w    = (const float*)d_in[1];
    const float* bias = (const float*)d_in[2];

    float* out_w = (float*)d_out;
    float* out_i = out_w + (size_t)T_TOKENS * TOPK;

    dim3 grid(T_TOKENS / BM);
    dim3 block(THREADS);
    gate_kernel<<<grid, block, 0, stream>>>(x, w, bias, out_w, out_i);
}

// Round 3
// 1410.591 us; speedup vs baseline: 3.7036x; 1.5424x over previous
//
#include <hip/hip_runtime.h>
#include <math.h>

#define T_TOKENS 16384
#define DIM      7168
#define NE       256
#define NG       8
#define GSZ      32
#define TOPKG    4
#define TOPK     8
#define RSCALE   2.5

#define NT      4           // tokens per wave
#define BM      (8 * NT)    // 32 tokens per block
#define BK      16
#define THREADS 512
#define NTILES  (DIM / BK)  // 448

typedef float v2f __attribute__((ext_vector_type(2)));

// R2 post-mortem: spill gone (WRITE_SIZE 14.6 GB -> 1 MB), fp64-VALU-bound at
// ~1900 us (fp64 FMA floor ~765 us at 78.6 TF). R3: the accuracy requirement is
// only "no top-k flips vs fp32 reference" -- chunked fp32 accumulation (32
// products per chunk, fp64 fold every 2 tiles) has ~1e-6 absolute score error,
// 10x BELOW the reference's own fp32 summation noise (~1e-5), at fp32 rate
// (2 cy/wave-FMA, 1 cy if the backend packs v_pk_fma_f32).
__global__ __launch_bounds__(THREADS)
__attribute__((amdgpu_waves_per_eu(2, 4)))
void gate_kernel(
    const float* __restrict__ x,      // [T][DIM] fp32
    const float* __restrict__ w,      // [NE][DIM] fp32
    const float* __restrict__ bias,   // [NE] fp32
    float* __restrict__ out_w,        // [T][8]
    float* __restrict__ out_i)        // [T][8] (indices as float)
{
#pragma clang fp contract(fast)
    // Bs[kk][pos] fp32, pos = half*128 + lane*2 + j  <->  expert e = half*128 + j*64 + lane
    __shared__ __align__(16) float  Bs[BK * NE];     // 16 KB
    __shared__ __align__(16) double scr[8 * NE];     // 16 KB: per-wave unbiased sigmoid
    __shared__ __align__(16) double bias_d[NE];      // 2 KB

    const int tid  = threadIdx.x;
    const int lane = tid & 63;
    const int wave_u = __builtin_amdgcn_readfirstlane(tid >> 6);  // 0..7, uniform

    if (tid < NE) bias_d[tid] = (double)bias[tid];

    // ---- staging role: this thread loads experts (e0,e1) at k-chunk kc_s ----
    const int half = wave_u >> 2;     // 0/1
    const int kc_s = wave_u & 3;      // 0..3
    const int e0   = half * 128 + lane;
    const int e1   = e0 + 64;
    const float* wp0 = w + (size_t)e0 * DIM + kc_s * 4;
    const float* wp1 = w + (size_t)e1 * DIM + kc_s * 4;

    const int tok_base = blockIdx.x * BM + wave_u * NT;   // uniform per wave

    double acc[NT][4];
#pragma unroll
    for (int t = 0; t < NT; ++t)
#pragma unroll
        for (int j = 0; j < 4; ++j) acc[t][j] = 0.0;

    // fp32 chunk accumulators (folded into acc every 2 tiles = 32 products)
    v2f c01[NT], c23[NT];
#pragma unroll
    for (int t = 0; t < NT; ++t) { c01[t] = (v2f)0.f; c23[t] = (v2f)0.f; }

    // prefetch B tile 0 into regs
    float4 f0 = *(const float4*)(wp0);
    float4 f1 = *(const float4*)(wp1);

    // prefetch A chunk (kc=0 of tile 0): wave-uniform addresses
    float4 a_cur[NT], a_nxt[NT];
#pragma unroll
    for (int t = 0; t < NT; ++t)
        a_cur[t] = *(const float4*)(x + (size_t)(tok_base + t) * DIM);

    for (int tile = 0; tile < NTILES; ++tile) {
        const int k0 = tile * BK;

        __syncthreads();   // previous tile's Bs reads complete (also covers bias_d init)
#pragma unroll
        for (int c = 0; c < 4; ++c) {
            v2f d;
            d[0] = (&f0.x)[c];
            d[1] = (&f1.x)[c];
            *(v2f*)&Bs[(kc_s * 4 + c) * NE + half * 128 + lane * 2] = d;
        }
        __syncthreads();   // Bs ready

        if (tile + 1 < NTILES) {       // register-prefetch next B tile
            f0 = *(const float4*)(wp0 + (size_t)(tile + 1) * BK);
            f1 = *(const float4*)(wp1 + (size_t)(tile + 1) * BK);
        }

#pragma unroll
        for (int kc = 0; kc < 4; ++kc) {
            int knext = k0 + (kc + 1) * 4;       // at kc=3 this is next tile's chunk 0
            if (knext >= DIM) knext = 0;         // last-tile guard (values discarded)
#pragma unroll
            for (int t = 0; t < NT; ++t)
                a_nxt[t] = *(const float4*)(x + (size_t)(tok_base + t) * DIM + knext);

#pragma unroll
            for (int c = 0; c < 4; ++c) {
                const int kk = kc * 4 + c;
                v2f b01 = *(const v2f*)&Bs[kk * NE + lane * 2];
                v2f b23 = *(const v2f*)&Bs[kk * NE + 128 + lane * 2];
#pragma unroll
                for (int t = 0; t < NT; ++t) {
                    float a = (&a_cur[t].x)[c];
                    v2f av; av[0] = a; av[1] = a;
                    c01[t] = av * b01 + c01[t];   // contract(fast) -> pk/fma
                    c23[t] = av * b23 + c23[t];
                }
            }
#pragma unroll
            for (int t = 0; t < NT; ++t) a_cur[t] = a_nxt[t];
        }

        if (tile & 1) {    // fold fp32 chunk (32 products) into fp64 accumulator
#pragma unroll
            for (int t = 0; t < NT; ++t) {
                acc[t][0] += (double)c01[t][0];
                acc[t][1] += (double)c01[t][1];
                acc[t][2] += (double)c23[t][0];
                acc[t][3] += (double)c23[t][1];
                c01[t] = (v2f)0.f;
                c23[t] = (v2f)0.f;
            }
        }
    }

    // ================= routing (per-wave independent, fp64) =================
    double* myscr = scr + wave_u * NE;

    double bias_j[4];
#pragma unroll
    for (int j = 0; j < 4; ++j) bias_j[j] = bias_d[j * 64 + lane];

    for (int tk = 0; tk < NT; ++tk) {
        // sigmoid (fp64) of this token's 4 expert scores; stash unbiased in LDS
        double sg[4];
#pragma unroll
        for (int j = 0; j < 4; ++j) {
            sg[j] = 1.0 / (1.0 + exp(-acc[tk][j]));
            myscr[j * 64 + lane] = sg[j];
        }
        asm volatile("s_waitcnt lgkmcnt(0)" ::: "memory");  // same-wave LDS visibility

        // ---- group scores: top-2 sum of biased scores per group (8 lanes/group) ----
        const int g    = lane >> 3;
        const int slot = lane & 7;
        const int eb   = g * GSZ + slot * 4;
        double2 s01  = *(const double2*)&myscr[eb];
        double2 s23  = *(const double2*)&myscr[eb + 2];
        double2 b01v = *(const double2*)&bias_d[eb];
        double2 b23v = *(const double2*)&bias_d[eb + 2];
        double c0 = s01.x + b01v.x, c1 = s01.y + b01v.y;
        double c2 = s23.x + b23v.x, c3 = s23.y + b23v.y;
        double m1 = fmax(c0, c1), m2 = fmin(c0, c1);
        if (c2 > m1) { m2 = m1; m1 = c2; } else m2 = fmax(m2, c2);
        if (c3 > m1) { m2 = m1; m1 = c3; } else m2 = fmax(m2, c3);
#pragma unroll
        for (int off = 1; off <= 4; off <<= 1) {
            double o1 = __shfl_xor(m1, off);
            double o2 = __shfl_xor(m2, off);
            double nm1 = fmax(m1, o1);
            double nm2 = fmax(fmin(m1, o1), fmax(m2, o2));
            m1 = nm1; m2 = nm2;
        }
        double gs_local = m1 + m2;
        double gsv[NG];
#pragma unroll
        for (int gg = 0; gg < NG; ++gg) gsv[gg] = __shfl(gs_local, gg * 8);

        // top-4 groups (stable: ties -> lower group index)
        int selmask = 0;
#pragma unroll
        for (int gg = 0; gg < NG; ++gg) {
            int rank = 0;
#pragma unroll
            for (int h = 0; h < NG; ++h)
                if (gsv[h] > gsv[gg] || (gsv[h] == gsv[gg] && h < gg)) rank++;
            if (rank < TOPKG) selmask |= (1 << gg);
        }

        // ---- top-8 experts: register-resident butterfly extraction ----
        double cv[4];
#pragma unroll
        for (int j = 0; j < 4; ++j) {
            int grp = j * 2 + (lane >> 5);       // group of expert j*64+lane
            cv[j] = ((selmask >> grp) & 1) ? (sg[j] + bias_j[j]) : -INFINITY;
        }

        double ssum = 0.0, my_u = 0.0;
        int my_i = 0;
#pragma unroll
        for (int r = 0; r < TOPK; ++r) {
            double bv = cv[0], bu = sg[0];
            int bi = lane;
#pragma unroll
            for (int j = 1; j < 4; ++j) {
                if (cv[j] > bv) { bv = cv[j]; bu = sg[j]; bi = j * 64 + lane; }
            }
#pragma unroll
            for (int off = 1; off < 64; off <<= 1) {
                double ov = __shfl_xor(bv, off);
                double ou = __shfl_xor(bu, off);
                int    oi = __shfl_xor(bi, off);
                if (ov > bv || (ov == bv && oi < bi)) { bv = ov; bu = ou; bi = oi; }
            }
            ssum += bu;
            if (lane == r) { my_u = bu; my_i = bi; }
#pragma unroll
            for (int j = 0; j < 4; ++j)
                if (j * 64 + lane == bi) cv[j] = -INFINITY;
        }

        const double scale = RSCALE / ssum;
        const size_t obase = (size_t)(tok_base + tk) * TOPK;
        if (lane < TOPK) {
            out_w[obase + lane] = (float)(my_u * scale);
            out_i[obase + lane] = (float)my_i;
        }
    }
}

extern "C" void kernel_launch(void* const* d_in, const int* in_sizes, int n_in,
                              void* d_out, int out_size, void* d_ws, size_t ws_size,
                              hipStream_t stream) {
    const float* x    = (const float*)d_in[0];
    const float* w    = (const float*)d_in[1];
    const float* bias = (const float*)d_in[2];

    float* out_w = (float*)d_out;
    float* out_i = out_w + (size_t)T_TOKENS * TOPK;

    dim3 grid(T_TOKENS / BM);
    dim3 block(THREADS);
    gate_kernel<<<grid, block, 0, stream>>>(x, w, bias, out_w, out_i);
}